// Round 1
// baseline (21197.406 us; speedup 1.0000x reference)
//
#include <hip/hip_runtime.h>

// LSTM_71167608094989: 2-layer LSTM, T=512, B=64, I=H=1024, eval mode.
// Round 1 design: fp16 MFMA, fused K=2048 per-step GEMM (wcat = [w_ih; w_hh]),
// one kernel launch per step with both layers diagonally pipelined
// (layer0 step s + layer1 step s-1). 513 step launches total.

typedef _Float16 h8_t __attribute__((ext_vector_type(8)));
typedef _Float16 h4_t __attribute__((ext_vector_type(4)));
typedef float f4_t __attribute__((ext_vector_type(4)));

#define T_STEPS 512
#define BATCH 64
#define HID 1024
#define STEP_ELEMS (BATCH * HID)   // 65536

// ---------------- conversion kernels ----------------

__global__ void k_f32_to_f16(const float* __restrict__ src, _Float16* __restrict__ dst) {
    size_t i = ((size_t)blockIdx.x * blockDim.x + threadIdx.x) * 4;
    float4 v = *(const float4*)(src + i);
    h4_t h = { (_Float16)v.x, (_Float16)v.y, (_Float16)v.z, (_Float16)v.w };
    *(h4_t*)(dst + i) = h;
}

// wcat[n][k], n in [0,4096), k in [0,2048): k<1024 -> w_ih[n][k], else w_hh[n][k-1024]
__global__ void k_build_wcat(const float* __restrict__ w_ih, const float* __restrict__ w_hh,
                             _Float16* __restrict__ wcat) {
    size_t i = ((size_t)blockIdx.x * blockDim.x + threadIdx.x) * 4;
    int n = (int)(i >> 11);
    int k = (int)(i & 2047);
    const float* src = (k < 1024) ? (w_ih + (size_t)n * 1024 + k)
                                  : (w_hh + (size_t)n * 1024 + (k - 1024));
    float4 v = *(const float4*)src;
    h4_t h = { (_Float16)v.x, (_Float16)v.y, (_Float16)v.z, (_Float16)v.w };
    *(h4_t*)(wcat + i) = h;
}

__global__ void k_bias(const float* __restrict__ a, const float* __restrict__ b,
                       float* __restrict__ o) {
    int i = blockIdx.x * blockDim.x + threadIdx.x;
    o[i] = a[i] + b[i];
}

// ---------------- LSTM step kernel ----------------

__device__ __forceinline__ float sigmf(float x) { return 1.0f / (1.0f + __expf(-x)); }

// grid = 128 blocks x 256 threads.
//   blocks 0..63  : layer slot 0 (active if mask&1), hidden units u0 = blk*16
//   blocks 64..127: layer slot 1 (active if mask&2), hidden units u0 = (blk-64)*16
// Per block: gates[64 batch rows][16 units x 4 gates], K = 2048 ( [x_t ; h_prev] ).
// 4 waves, wave w owns batch rows 16w..16w+15; 4 MFMA N-tiles = gates i,f,g,o.
__global__ __launch_bounds__(256) void lstm_step2(
    const _Float16* __restrict__ xin0, const _Float16* __restrict__ hp0,
    const _Float16* __restrict__ wc0, const float* __restrict__ bb0,
    float* __restrict__ cb0, _Float16* __restrict__ ho0,
    const _Float16* __restrict__ xin1, const _Float16* __restrict__ hp1,
    const _Float16* __restrict__ wc1, const float* __restrict__ bb1,
    float* __restrict__ cb1, _Float16* __restrict__ ho1,
    float* __restrict__ of1, int mask)
{
    int blk = blockIdx.x;
    const _Float16 *xin, *hp, *wc;
    const float* bb;
    float* cbuf;
    _Float16* hf;
    float* hf32 = nullptr;
    int u0;
    if (blk < 64) {
        if (!(mask & 1)) return;
        xin = xin0; hp = hp0; wc = wc0; bb = bb0; cbuf = cb0; hf = ho0;
        u0 = blk * 16;
    } else {
        if (!(mask & 2)) return;
        xin = xin1; hp = hp1; wc = wc1; bb = bb1; cbuf = cb1; hf = ho1;
        hf32 = of1;
        u0 = (blk - 64) * 16;
    }

    const int lane = threadIdx.x & 63;
    const int wave = threadIdx.x >> 6;
    const int q = lane >> 4;      // quad 0..3
    const int m16 = lane & 15;    // row-in-tile (A) / col-in-tile (B)
    const int r = wave * 16 + m16; // batch row for A loads

    f4_t acc[4] = {};

    // B fragment rows: wcat row n = g*1024 + u0 + m16; k offset starts at q*8
    const _Float16* wrow[4];
#pragma unroll
    for (int g = 0; g < 4; ++g)
        wrow[g] = wc + (size_t)(g * 1024 + u0 + m16) * 2048 + q * 8;

    // Phase 1: x part (global k in [0,1024))
    {
        const _Float16* arow = xin + (size_t)r * 1024 + q * 8;
#pragma unroll 4
        for (int kk = 0; kk < 32; ++kk) {
            h8_t a = *(const h8_t*)(arow + kk * 32);
#pragma unroll
            for (int g = 0; g < 4; ++g) {
                h8_t b = *(const h8_t*)(wrow[g] + kk * 32);
                acc[g] = __builtin_amdgcn_mfma_f32_16x16x32_f16(a, b, acc[g], 0, 0, 0);
            }
        }
    }
    // Phase 2: h part (global k in [1024,2048))
    {
        const _Float16* arow = hp + (size_t)r * 1024 + q * 8;
#pragma unroll 4
        for (int kk = 0; kk < 32; ++kk) {
            h8_t a = *(const h8_t*)(arow + kk * 32);
#pragma unroll
            for (int g = 0; g < 4; ++g) {
                h8_t b = *(const h8_t*)(wrow[g] + 1024 + kk * 32);
                acc[g] = __builtin_amdgcn_mfma_f32_16x16x32_f16(a, b, acc[g], 0, 0, 0);
            }
        }
    }

    // Epilogue: acc[g][ri] = gate g, batch row wave*16 + q*4 + ri, unit u0+m16
    const int unit = u0 + m16;
    const float bi = bb[unit];
    const float bf = bb[1024 + unit];
    const float bg = bb[2048 + unit];
    const float bo = bb[3072 + unit];
#pragma unroll
    for (int ri = 0; ri < 4; ++ri) {
        int row = wave * 16 + q * 4 + ri;
        float iv = acc[0][ri] + bi;
        float fv = acc[1][ri] + bf;
        float gv = acc[2][ri] + bg;
        float ov = acc[3][ri] + bo;
        size_t idx = (size_t)row * HID + unit;
        float cn = sigmf(fv) * cbuf[idx] + sigmf(iv) * tanhf(gv);
        float hn = sigmf(ov) * tanhf(cn);
        cbuf[idx] = cn;
        hf[idx] = (_Float16)hn;
        if (hf32) hf32[idx] = hn;
    }
}

// ---------------- host orchestration ----------------

extern "C" void kernel_launch(void* const* d_in, const int* in_sizes, int n_in,
                              void* d_out, int out_size, void* d_ws, size_t ws_size,
                              hipStream_t stream) {
    const float* input = (const float*)d_in[0];
    const float* w_ih0 = (const float*)d_in[1];
    const float* w_hh0 = (const float*)d_in[2];
    const float* b_ih0 = (const float*)d_in[3];
    const float* b_hh0 = (const float*)d_in[4];
    const float* w_ih1 = (const float*)d_in[5];
    const float* w_hh1 = (const float*)d_in[6];
    const float* b_ih1 = (const float*)d_in[7];
    const float* b_hh1 = (const float*)d_in[8];
    float* out = (float*)d_out;

    // workspace partition (~236 MB total)
    char* p = (char*)d_ws;
    _Float16* x16 = (_Float16*)p;  p += (size_t)T_STEPS * STEP_ELEMS * 2;  // 67 MB
    _Float16* h1  = (_Float16*)p;  p += (size_t)T_STEPS * STEP_ELEMS * 2;  // 67 MB
    _Float16* h2  = (_Float16*)p;  p += (size_t)T_STEPS * STEP_ELEMS * 2;  // 67 MB
    _Float16* wc0 = (_Float16*)p;  p += (size_t)4096 * 2048 * 2;           // 16 MB
    _Float16* wc1 = (_Float16*)p;  p += (size_t)4096 * 2048 * 2;           // 16 MB
    float* bias0  = (float*)p;     p += 4096 * 4;
    float* bias1  = (float*)p;     p += 4096 * 4;
    float* c0     = (float*)p;     p += STEP_ELEMS * 4;
    float* c1     = (float*)p;     p += STEP_ELEMS * 4;
    _Float16* hz  = (_Float16*)p;  p += STEP_ELEMS * 2;

    hipMemsetAsync(c0, 0, STEP_ELEMS * 4, stream);
    hipMemsetAsync(c1, 0, STEP_ELEMS * 4, stream);
    hipMemsetAsync(hz, 0, STEP_ELEMS * 2, stream);

    // conversions
    k_f32_to_f16<<<(T_STEPS * STEP_ELEMS / 4) / 256, 256, 0, stream>>>(input, x16);
    k_build_wcat<<<(4096 * 2048 / 4) / 256, 256, 0, stream>>>(w_ih0, w_hh0, wc0);
    k_build_wcat<<<(4096 * 2048 / 4) / 256, 256, 0, stream>>>(w_ih1, w_hh1, wc1);
    k_bias<<<16, 256, 0, stream>>>(b_ih0, b_hh0, bias0);
    k_bias<<<16, 256, 0, stream>>>(b_ih1, b_hh1, bias1);

    // diagonal pipeline: launch s does layer0 step s and layer1 step s-1
    for (int s = 0; s <= T_STEPS; ++s) {
        int t1 = (s > 0) ? (s - 1) : 0;  // clamped; inactive when s==0
        const _Float16* xin0 = x16 + (size_t)s * STEP_ELEMS;         // valid when s<512
        const _Float16* hp0  = (s == 0) ? hz : h1 + (size_t)(s - 1) * STEP_ELEMS;
        _Float16* ho0        = h1 + (size_t)s * STEP_ELEMS;
        const _Float16* xin1 = h1 + (size_t)t1 * STEP_ELEMS;
        const _Float16* hp1  = (t1 == 0) ? hz : h2 + (size_t)(t1 - 1) * STEP_ELEMS;
        _Float16* ho1        = h2 + (size_t)t1 * STEP_ELEMS;
        float* of1           = out + (size_t)t1 * STEP_ELEMS;
        int mask = ((s < T_STEPS) ? 1 : 0) | ((s >= 1) ? 2 : 0);
        // clamp layer-0 x pointer at the final (inactive) iteration
        if (s == T_STEPS) xin0 = x16;
        lstm_step2<<<128, 256, 0, stream>>>(xin0, hp0, wc0, bias0, c0, ho0,
                                            xin1, hp1, wc1, bias1, c1, ho1,
                                            of1, mask);
    }
}